// Round 4
// baseline (305.425 us; speedup 1.0000x reference)
//
#include <hip/hip_runtime.h>

#define NE 8192
#define DD 256
#define NSPLIT 32
#define NB 256
#define MAGIC 0x13572468

typedef __attribute__((ext_vector_type(8))) short short8;
typedef __attribute__((ext_vector_type(4))) short short4v;
typedef __attribute__((ext_vector_type(8))) __bf16 bf16x8;
typedef __attribute__((ext_vector_type(4))) float floatx4;

__device__ __forceinline__ unsigned short f2bf(float f) {
  union { float f; unsigned int i; } v; v.f = f;
  unsigned int r = v.i + 0x7fffu + ((v.i >> 16) & 1u);
  return (unsigned short)(r >> 16);
}

__device__ __forceinline__ floatx4 mfma_bf16(short8 a, short8 b, floatx4 c) {
  return __builtin_amdgcn_mfma_f32_16x16x32_bf16(
      __builtin_bit_cast(bf16x8, a), __builtin_bit_cast(bf16x8, b), c, 0, 0, 0);
}

// grid-wide barrier: all NB blocks co-resident (256 blocks <= 256 CUs).
__device__ __forceinline__ void grid_barrier(int* cnt) {
  __syncthreads();
  if (threadIdx.x == 0) {
    __threadfence();   // agent-scope release of all prior global stores
    __hip_atomic_fetch_add(cnt, 1, __ATOMIC_ACQ_REL, __HIP_MEMORY_SCOPE_AGENT);
    while (__hip_atomic_load(cnt, __ATOMIC_ACQUIRE, __HIP_MEMORY_SCOPE_AGENT) < NB)
      __builtin_amdgcn_s_sleep(1);
  }
  __syncthreads();
}

// 64x64 fp32->bf16 transpose tile via LDS (lsf = 64x68 floats in shared pool)
__device__ __forceinline__ void tcvt_tile(float* lsf,
                                          const float* __restrict__ src, int C,
                                          unsigned short* __restrict__ dst, int R,
                                          int r0, int c0, int tid) {
  const int rr = tid >> 4;
  const int c4 = (tid & 15) * 4;
#pragma unroll
  for (int k = 0; k < 4; ++k)
    *(floatx4*)&lsf[(rr + k * 16) * 68 + c4] =
        *(const floatx4*)&src[(size_t)(r0 + rr + k * 16) * C + c0 + c4];
  __syncthreads();
  const int cc = tid >> 2;
  const int rb = (tid & 3) * 16;
  short8 o0, o1;
#pragma unroll
  for (int i = 0; i < 8; ++i) {
    o0[i] = (short)f2bf(lsf[(rb + i) * 68 + cc]);
    o1[i] = (short)f2bf(lsf[(rb + 8 + i) * 68 + cc]);
  }
  unsigned short* dp = &dst[(size_t)(c0 + cc) * R + r0 + rb];
  *(short8*)dp = o0;
  *(short8*)(dp + 8) = o1;
  __syncthreads();
}

__global__ __launch_bounds__(256, 2)
void mp_mega(const float* __restrict__ x,
             const float* __restrict__ W1, const float* __restrict__ b1,
             const float* __restrict__ W2, const float* __restrict__ b2,
             const float* __restrict__ W3, const float* __restrict__ b3,
             float* __restrict__ out,
             unsigned short* __restrict__ xb, unsigned short* __restrict__ xT,
             unsigned short* __restrict__ e1, unsigned short* __restrict__ e2,
             unsigned short* __restrict__ e1T, unsigned short* __restrict__ e2T,
             unsigned short* __restrict__ W1t, unsigned short* __restrict__ W2t,
             unsigned short* __restrict__ W3t0,
             unsigned short* __restrict__ H1t, unsigned short* __restrict__ H2t,
             float* __restrict__ G_T, float* __restrict__ P_T,
             int* __restrict__ sync)
{
  __shared__ __align__(16) unsigned short sm[2 * 128 * 40];   // 20480 B pool
  unsigned short* lds_a = sm;
  unsigned short* lds_b = sm + 128 * 40;
  float* lsf = (float*)sm;

  const int B = blockIdx.x;
  const int T = threadIdx.x;
  const int lane = T & 63;
  const int wv = T >> 6;
  const int q = lane >> 4, r = lane & 15;

  // ---- init: block 0 zeroes barrier counters (ws is poisoned 0xAA), then
  // releases everyone via MAGIC flag.
  if (B == 0 && T == 0) {
    for (int i = 1; i <= 6; ++i)
      __hip_atomic_store(&sync[i], 0, __ATOMIC_RELAXED, __HIP_MEMORY_SCOPE_AGENT);
    __hip_atomic_store(&sync[0], MAGIC, __ATOMIC_RELEASE, __HIP_MEMORY_SCOPE_AGENT);
  }
  if (T == 0) {
    while (__hip_atomic_load(&sync[0], __ATOMIC_ACQUIRE, __HIP_MEMORY_SCOPE_AGENT) != MAGIC)
      __builtin_amdgcn_s_sleep(1);
  }
  __syncthreads();

  // ================= P0: conversions =================
  // straight fp32->bf16 of x (8192x256): 262144 groups of 8
#pragma unroll
  for (int p = 0; p < 4; ++p) {
    int i = (p * NB + B) * 256 + T;
    floatx4 a = ((const floatx4*)x)[2 * i];
    floatx4 c = ((const floatx4*)x)[2 * i + 1];
    short8 o;
#pragma unroll
    for (int k = 0; k < 4; ++k) { o[k] = (short)f2bf(a[k]); o[4 + k] = (short)f2bf(c[k]); }
    ((short8*)xb)[i] = o;
  }
  // xT: 512 tiles, 2 per block
#pragma unroll
  for (int tt = 0; tt < 2; ++tt) {
    int t = B * 2 + tt;
    tcvt_tile(lsf, x, DD, xT, NE, (t >> 2) * 64, (t & 3) * 64, T);
  }
  // W1t/W2t/W3t0: 48 tiles on blocks 0..47
  if (B < 48) {
    int t = B & 15;
    const float* src = (B < 16) ? W1 : ((B < 32) ? W2 : W3);
    unsigned short* dst = (B < 16) ? W1t : ((B < 32) ? W2t : W3t0);
    tcvt_tile(lsf, src, DD, dst, DD, (t >> 2) * 64, (t & 3) * 64, T);
  }
  grid_barrier(&sync[1]);

  // ================= P1: e-GEMM (e_z = relu(x@W_z + b_z)), 256 blocks =====
  {
    const int z = B >> 7, t = B & 127;
    const int col0 = (t & 1) * 128, row0 = (t >> 1) * 128;
    const unsigned short* Bop = z ? W2t : W1t;
    const float* bi = z ? b2 : b1;
    unsigned short* eo = z ? e2 : e1;
    unsigned short* eoT = z ? e2T : e1T;
    const int wr = (wv >> 1) * 64, wc = (wv & 1) * 64;

    floatx4 acc[4][4];
#pragma unroll
    for (int i = 0; i < 4; ++i)
#pragma unroll
      for (int j = 0; j < 4; ++j) acc[i][j] = (floatx4){0.f, 0.f, 0.f, 0.f};

    const int sr = T >> 1;
    const int sk = (T & 1) * 16;
    for (int kc = 0; kc < 256; kc += 32) {
      const unsigned short* ga = xb + (size_t)(row0 + sr) * DD + kc + sk;
      short8 av0 = *(const short8*)ga;
      short8 av1 = *(const short8*)(ga + 8);
      const unsigned short* gb = Bop + (size_t)(col0 + sr) * DD + kc + sk;
      short8 bv0 = *(const short8*)gb;
      short8 bv1 = *(const short8*)(gb + 8);
      *(short8*)&lds_a[sr * 40 + sk] = av0;
      *(short8*)&lds_a[sr * 40 + sk + 8] = av1;
      *(short8*)&lds_b[sr * 40 + sk] = bv0;
      *(short8*)&lds_b[sr * 40 + sk + 8] = bv1;
      __syncthreads();
      short8 af[4], bfr[4];
#pragma unroll
      for (int i = 0; i < 4; ++i)
        af[i] = *(const short8*)&lds_a[(wr + i * 16 + r) * 40 + q * 8];
#pragma unroll
      for (int j = 0; j < 4; ++j)
        bfr[j] = *(const short8*)&lds_b[(wc + j * 16 + r) * 40 + q * 8];
#pragma unroll
      for (int i = 0; i < 4; ++i)
#pragma unroll
        for (int j = 0; j < 4; ++j)
          acc[i][j] = mfma_bf16(af[i], bfr[j], acc[i][j]);
      __syncthreads();
    }
#pragma unroll
    for (int j = 0; j < 4; ++j) {
      const int col = col0 + wc + j * 16 + r;
      const float bv = bi[col];
#pragma unroll
      for (int i = 0; i < 4; ++i) {
        const int rowb = row0 + wr + i * 16 + q * 4;
        float v[4];
        short4v tv;
#pragma unroll
        for (int t2 = 0; t2 < 4; ++t2) {
          v[t2] = fmaxf(acc[i][j][t2] + bv, 0.0f);
          unsigned short h = f2bf(v[t2]);
          tv[t2] = (short)h;
          eo[(size_t)(rowb + t2) * DD + col] = h;
        }
        *(short4v*)&eoT[(size_t)col * NE + rowb] = tv;
      }
    }
  }
  grid_barrier(&sync[2]);

  // ================= P2: partial G^T = e_z^T @ x (split-K), 256 blocks ====
  {
    const int z = B >> 7, rest = B & 127;
    const int quad = rest & 3, split = rest >> 2;
    const int m0 = (quad >> 1) * 128, n0 = (quad & 1) * 128;
    const int j0 = split * (NE / NSPLIT);
    const unsigned short* E = z ? e2T : e1T;
    float* P = P_T + (size_t)(z * NSPLIT + split) * 65536;
    const int wr = (wv >> 1) * 64, wc = (wv & 1) * 64;

    floatx4 acc[4][4];
#pragma unroll
    for (int i = 0; i < 4; ++i)
#pragma unroll
      for (int j = 0; j < 4; ++j) acc[i][j] = (floatx4){0.f, 0.f, 0.f, 0.f};

    const int sr = T >> 1;
    const int sk = (T & 1) * 16;
    for (int jc = 0; jc < NE / NSPLIT; jc += 32) {
      const unsigned short* ge = E + (size_t)(m0 + sr) * NE + j0 + jc + sk;
      short8 ev0 = *(const short8*)ge;
      short8 ev1 = *(const short8*)(ge + 8);
      const unsigned short* gx = xT + (size_t)(n0 + sr) * NE + j0 + jc + sk;
      short8 xv0 = *(const short8*)gx;
      short8 xv1 = *(const short8*)(gx + 8);
      *(short8*)&lds_a[sr * 40 + sk] = ev0;
      *(short8*)&lds_a[sr * 40 + sk + 8] = ev1;
      *(short8*)&lds_b[sr * 40 + sk] = xv0;
      *(short8*)&lds_b[sr * 40 + sk + 8] = xv1;
      __syncthreads();
      short8 af[4], bfr[4];
#pragma unroll
      for (int i = 0; i < 4; ++i)
        af[i] = *(const short8*)&lds_a[(wr + i * 16 + r) * 40 + q * 8];
#pragma unroll
      for (int j = 0; j < 4; ++j)
        bfr[j] = *(const short8*)&lds_b[(wc + j * 16 + r) * 40 + q * 8];
#pragma unroll
      for (int i = 0; i < 4; ++i)
#pragma unroll
        for (int j = 0; j < 4; ++j)
          acc[i][j] = mfma_bf16(af[i], bfr[j], acc[i][j]);
      __syncthreads();
    }
#pragma unroll
    for (int i = 0; i < 4; ++i)
#pragma unroll
      for (int j = 0; j < 4; ++j) {
        const int n = n0 + wc + j * 16 + r;
        const int m = m0 + wr + i * 16 + q * 4;
        *(floatx4*)&P[(size_t)n * DD + m] = acc[i][j];
      }
  }
  grid_barrier(&sync[3]);

  // ================= P3: reduce P -> G_T (32768 floatx4), 256 blocks ======
  if (T < 128) {
    int idx = B * 128 + T;
    int z = idx >> 14, off = idx & 16383;
    const floatx4* Pp = (const floatx4*)P_T;
    floatx4 s = (floatx4){0.f, 0.f, 0.f, 0.f};
#pragma unroll
    for (int y = 0; y < NSPLIT; ++y)
      s += Pp[(size_t)(z * NSPLIT + y) * 16384 + off];
    ((floatx4*)G_T)[idx] = s;
  }
  grid_barrier(&sync[4]);

  // ================= P4: H_t = ((G/256) @ W3seg)^T, blocks 0..31 ==========
  if (B < 32) {
    float* lg = (float*)sm;
    float* lw = (float*)sm + 32 * 68;
    const int z = B >> 4, rr = B & 15;
    const int m0 = (rr & 3) * 64, k0 = (rr >> 2) * 64;
    const float* G = G_T + (size_t)z * 65536;
    unsigned short* Ht = z ? H2t : H1t;
    const float* Wb = W3 + (size_t)(256 + z * 256) * DD;
    const int ty = T >> 4, tx = T & 15;
    float acc[4][4] = {};
    for (int lc = 0; lc < 256; lc += 32) {
      int lr = T >> 3;
      int e8 = (T & 7) * 8;
      const float* gp = G + (size_t)(lc + lr) * DD + k0 + e8;
      *(floatx4*)&lg[lr * 68 + e8] = *(const floatx4*)gp;
      *(floatx4*)&lg[lr * 68 + e8 + 4] = *(const floatx4*)(gp + 4);
      const float* wp = Wb + (size_t)(lc + lr) * DD + m0 + e8;
      *(floatx4*)&lw[lr * 68 + e8] = *(const floatx4*)wp;
      *(floatx4*)&lw[lr * 68 + e8 + 4] = *(const floatx4*)(wp + 4);
      __syncthreads();
#pragma unroll
      for (int l = 0; l < 32; ++l) {
        float a[4], b[4];
#pragma unroll
        for (int i = 0; i < 4; ++i) a[i] = lg[l * 68 + ty * 4 + i];
#pragma unroll
        for (int j = 0; j < 4; ++j) b[j] = lw[l * 68 + tx * 4 + j];
#pragma unroll
        for (int i = 0; i < 4; ++i)
#pragma unroll
          for (int j = 0; j < 4; ++j) acc[i][j] = fmaf(a[i], b[j], acc[i][j]);
      }
      __syncthreads();
    }
#pragma unroll
    for (int j = 0; j < 4; ++j) {
      short4v tv;
#pragma unroll
      for (int i = 0; i < 4; ++i) tv[i] = (short)f2bf(acc[i][j] * 0.00390625f);
      *(short4v*)&Ht[(size_t)(m0 + tx * 4 + j) * DD + k0 + ty * 4] = tv;
    }
  }
  grid_barrier(&sync[5]);

  // ================= P5: out = relu(x@W3a + e1@H1 + e2@H2 + b3) ===========
  // 64x128 tiles so all 256 blocks participate; wave = 64 rows x 32 cols.
  {
    const int col0 = (B & 1) * 128;
    const int row0 = (B >> 1) * 64;
    const unsigned short* As[3] = {xb, e1, e2};
    const unsigned short* Bs[3] = {W3t0, H1t, H2t};

    floatx4 acc[4][2];
#pragma unroll
    for (int i = 0; i < 4; ++i)
#pragma unroll
      for (int j = 0; j < 2; ++j) acc[i][j] = (floatx4){0.f, 0.f, 0.f, 0.f};

    const int arow = T >> 2, ak8 = (T & 3) * 8;
    const int bn = T >> 1, bk16 = (T & 1) * 16;
    for (int s = 0; s < 3; ++s) {
      const unsigned short* A = As[s];
      const unsigned short* Bo = Bs[s];
      for (int kc = 0; kc < 256; kc += 32) {
        short8 av = *(const short8*)(A + (size_t)(row0 + arow) * DD + kc + ak8);
        const unsigned short* gb = Bo + (size_t)(col0 + bn) * DD + kc + bk16;
        short8 bv0 = *(const short8*)gb;
        short8 bv1 = *(const short8*)(gb + 8);
        *(short8*)&lds_a[arow * 40 + ak8] = av;
        *(short8*)&lds_b[bn * 40 + bk16] = bv0;
        *(short8*)&lds_b[bn * 40 + bk16 + 8] = bv1;
        __syncthreads();
        short8 af[4], bfr[2];
#pragma unroll
        for (int i = 0; i < 4; ++i)
          af[i] = *(const short8*)&lds_a[(i * 16 + r) * 40 + q * 8];
#pragma unroll
        for (int j = 0; j < 2; ++j)
          bfr[j] = *(const short8*)&lds_b[(wv * 32 + j * 16 + r) * 40 + q * 8];
#pragma unroll
        for (int i = 0; i < 4; ++i)
#pragma unroll
          for (int j = 0; j < 2; ++j)
            acc[i][j] = mfma_bf16(af[i], bfr[j], acc[i][j]);
        __syncthreads();
      }
    }
#pragma unroll
    for (int j = 0; j < 2; ++j) {
      const int col = col0 + wv * 32 + j * 16 + r;
      const float bv = b3[col];
#pragma unroll
      for (int i = 0; i < 4; ++i) {
        const int rowb = row0 + i * 16 + q * 4;
#pragma unroll
        for (int t2 = 0; t2 < 4; ++t2)
          out[(size_t)(rowb + t2) * DD + col] = fmaxf(acc[i][j][t2] + bv, 0.0f);
      }
    }
  }
}

// ---------------------------------------------------------------------------
extern "C" void kernel_launch(void* const* d_in, const int* in_sizes, int n_in,
                              void* d_out, int out_size, void* d_ws, size_t ws_size,
                              hipStream_t stream) {
  (void)in_sizes; (void)n_in; (void)out_size; (void)ws_size;
  const float* x  = (const float*)d_in[3];
  const float* W1 = (const float*)d_in[5];
  const float* b1 = (const float*)d_in[6];
  const float* W2 = (const float*)d_in[7];
  const float* b2 = (const float*)d_in[8];
  const float* W3 = (const float*)d_in[9];
  const float* b3 = (const float*)d_in[10];
  float* out = (float*)d_out;

  char* ws = (char*)d_ws;
  const size_t MB = 1u << 20;
  const size_t KB = 1u << 10;
  unsigned short* xb   = (unsigned short*)ws;                          // 4 MB
  unsigned short* xT   = (unsigned short*)(ws + 4 * MB);               // 4 MB
  unsigned short* e1   = (unsigned short*)(ws + 8 * MB);               // 4 MB
  unsigned short* e2   = (unsigned short*)(ws + 12 * MB);              // 4 MB
  unsigned short* e1T  = (unsigned short*)(ws + 16 * MB);              // 4 MB
  unsigned short* e2T  = (unsigned short*)(ws + 20 * MB);              // 4 MB
  unsigned short* W1t  = (unsigned short*)(ws + 24 * MB);              // 128 KB
  unsigned short* W2t  = (unsigned short*)(ws + 24 * MB + 128 * KB);   // 128 KB
  unsigned short* W3t0 = (unsigned short*)(ws + 24 * MB + 256 * KB);   // 128 KB
  unsigned short* H1t  = (unsigned short*)(ws + 24 * MB + 384 * KB);   // 128 KB
  unsigned short* H2t  = (unsigned short*)(ws + 24 * MB + 512 * KB);   // 128 KB
  float* G_T           = (float*)(ws + 24 * MB + 640 * KB);            // 512 KB
  float* P_T           = (float*)(ws + 26 * MB);                       // 16 MB
  int* sync            = (int*)(ws + 48 * MB);                         // 64 B

  mp_mega<<<NB, 256, 0, stream>>>(x, W1, b1, W2, b2, W3, b3, out,
                                  xb, xT, e1, e2, e1T, e2T,
                                  W1t, W2t, W3t0, H1t, H2t, G_T, P_T, sync);
}

// Round 5
// 167.872 us; speedup vs baseline: 1.8194x; 1.8194x over previous
//
#include <hip/hip_runtime.h>

#define NE 8192
#define DD 256
#define NSPLIT 32

typedef __attribute__((ext_vector_type(8))) short short8;
typedef __attribute__((ext_vector_type(4))) short short4v;
typedef __attribute__((ext_vector_type(8))) __bf16 bf16x8;
typedef __attribute__((ext_vector_type(4))) float floatx4;

__device__ __forceinline__ unsigned short f2bf(float f) {
  union { float f; unsigned int i; } v; v.f = f;
  unsigned int r = v.i + 0x7fffu + ((v.i >> 16) & 1u);
  return (unsigned short)(r >> 16);
}

__device__ __forceinline__ floatx4 mfma_bf16(short8 a, short8 b, floatx4 c) {
  return __builtin_amdgcn_mfma_f32_16x16x32_bf16(
      __builtin_bit_cast(bf16x8, a), __builtin_bit_cast(bf16x8, b), c, 0, 0, 0);
}

// ---------------------------------------------------------------------------
// K1: e_z = relu(x @ W_z + b_z), z in {0,1}. Tile 128x128, BK=64.
// A staged fp32->bf16 on the fly; B (W fp32 [k][n]) self-transposed in LDS.
// z==0,col0==0 blocks also emit xT[k][row] bf16. Epilogue stores e and e^T.
__global__ __launch_bounds__(256, 1)
void e_gemm(const float* __restrict__ x,
            const float* __restrict__ W1, const float* __restrict__ b1,
            const float* __restrict__ W2, const float* __restrict__ b2,
            unsigned short* __restrict__ e1, unsigned short* __restrict__ e2,
            unsigned short* __restrict__ e1T, unsigned short* __restrict__ e2T,
            unsigned short* __restrict__ xT)
{
  __shared__ __align__(16) unsigned short smA[128 * 72];
  __shared__ __align__(16) unsigned short smB[128 * 72];
  const int T = threadIdx.x, lane = T & 63, wv = T >> 6;
  const int q = lane >> 4, r = lane & 15;
  const int z = blockIdx.z;
  const int col0 = blockIdx.x * 128, row0 = blockIdx.y * 128;
  const float* W = z ? W2 : W1;
  const float* bi = z ? b2 : b1;
  unsigned short* eo = z ? e2 : e1;
  unsigned short* eoT = z ? e2T : e1T;
  const bool emit = (z == 0) && (blockIdx.x == 0);
  const int wr = (wv >> 1) * 64, wc = (wv & 1) * 64;

  floatx4 acc[4][4];
#pragma unroll
  for (int i = 0; i < 4; ++i)
#pragma unroll
    for (int j = 0; j < 4; ++j) acc[i][j] = (floatx4){0.f, 0.f, 0.f, 0.f};

  for (int kc = 0; kc < 256; kc += 64) {
    // A: x[row0..+128][kc..+64] fp32 -> bf16 LDS [rr][k]
#pragma unroll
    for (int p = 0; p < 8; ++p) {
      const int rr = p * 16 + (T >> 4), k4 = (T & 15) * 4;
      floatx4 v = *(const floatx4*)&x[(size_t)(row0 + rr) * DD + kc + k4];
      short4v s;
#pragma unroll
      for (int c = 0; c < 4; ++c) s[c] = (short)f2bf(v[c]);
      *(short4v*)&smA[rr * 72 + k4] = s;
    }
    // B: W[kc+k][col0+n] fp32 -> LDS [n][k] (transpose)
    {
      const int n = T & 127, khalf = T >> 7;
#pragma unroll
      for (int p = 0; p < 32; ++p) {
        const int k = p * 2 + khalf;
        smB[n * 72 + k] = f2bf(W[(size_t)(kc + k) * DD + col0 + n]);
      }
    }
    __syncthreads();
#pragma unroll
    for (int ks = 0; ks < 2; ++ks) {
      short8 af[4], bf[4];
#pragma unroll
      for (int i = 0; i < 4; ++i)
        af[i] = *(const short8*)&smA[(wr + i * 16 + r) * 72 + ks * 32 + q * 8];
#pragma unroll
      for (int j = 0; j < 4; ++j)
        bf[j] = *(const short8*)&smB[(wc + j * 16 + r) * 72 + ks * 32 + q * 8];
#pragma unroll
      for (int i = 0; i < 4; ++i)
#pragma unroll
        for (int j = 0; j < 4; ++j)
          acc[i][j] = mfma_bf16(af[i], bf[j], acc[i][j]);
    }
    if (emit) {  // xT[kc+kk][row0..+128] from smA (bf16 already)
      const int kk = T >> 2, seg = (T & 3) * 32;
#pragma unroll
      for (int s = 0; s < 4; ++s) {
        short8 v;
#pragma unroll
        for (int i = 0; i < 8; ++i)
          v[i] = (short)smA[(seg + s * 8 + i) * 72 + kk];
        *(short8*)&xT[(size_t)(kc + kk) * NE + row0 + seg + s * 8] = v;
      }
    }
    __syncthreads();
  }

#pragma unroll
  for (int j = 0; j < 4; ++j) {
    const int col = col0 + wc + j * 16 + r;
    const float bv = bi[col];
#pragma unroll
    for (int i = 0; i < 4; ++i) {
      const int rowb = row0 + wr + i * 16 + q * 4;
      short4v tv;
#pragma unroll
      for (int t2 = 0; t2 < 4; ++t2) {
        float v = fmaxf(acc[i][j][t2] + bv, 0.0f);
        unsigned short h = f2bf(v);
        tv[t2] = (short)h;
        eo[(size_t)(rowb + t2) * DD + col] = h;
      }
      *(short4v*)&eoT[(size_t)col * NE + rowb] = tv;
    }
  }
}

// ---------------------------------------------------------------------------
// K2: P_T[z*NSPLIT+split][n][m] = (e_z^T x)-slice. BK=64, all vectorized.
__global__ __launch_bounds__(256, 1)
void atb(const unsigned short* __restrict__ e1T, const unsigned short* __restrict__ e2T,
         const unsigned short* __restrict__ xT, float* __restrict__ P_T)
{
  __shared__ __align__(16) unsigned short smA[128 * 72];
  __shared__ __align__(16) unsigned short smB[128 * 72];
  const int T = threadIdx.x, lane = T & 63, wv = T >> 6;
  const int q = lane >> 4, r = lane & 15;
  const int quad = blockIdx.x, split = blockIdx.y, z = blockIdx.z;
  const int m0 = (quad >> 1) * 128, n0 = (quad & 1) * 128;
  const int j0 = split * 256;
  const unsigned short* E = z ? e2T : e1T;
  float* P = P_T + (size_t)(z * NSPLIT + split) * 65536;
  const int wr = (wv >> 1) * 64, wc = (wv & 1) * 64;

  floatx4 acc[4][4];
#pragma unroll
  for (int i = 0; i < 4; ++i)
#pragma unroll
    for (int j = 0; j < 4; ++j) acc[i][j] = (floatx4){0.f, 0.f, 0.f, 0.f};

  for (int jc = 0; jc < 256; jc += 64) {
#pragma unroll
    for (int p = 0; p < 4; ++p) {
      const int mm = p * 32 + (T >> 3), j8 = (T & 7) * 8;
      *(short8*)&smA[mm * 72 + j8] = *(const short8*)&E[(size_t)(m0 + mm) * NE + j0 + jc + j8];
      *(short8*)&smB[mm * 72 + j8] = *(const short8*)&xT[(size_t)(n0 + mm) * NE + j0 + jc + j8];
    }
    __syncthreads();
#pragma unroll
    for (int ks = 0; ks < 2; ++ks) {
      short8 af[4], bf[4];
#pragma unroll
      for (int i = 0; i < 4; ++i)
        af[i] = *(const short8*)&smA[(wr + i * 16 + r) * 72 + ks * 32 + q * 8];
#pragma unroll
      for (int j = 0; j < 4; ++j)
        bf[j] = *(const short8*)&smB[(wc + j * 16 + r) * 72 + ks * 32 + q * 8];
#pragma unroll
      for (int i = 0; i < 4; ++i)
#pragma unroll
        for (int j = 0; j < 4; ++j)
          acc[i][j] = mfma_bf16(af[i], bf[j], acc[i][j]);
    }
    __syncthreads();
  }
#pragma unroll
  for (int i = 0; i < 4; ++i)
#pragma unroll
    for (int j = 0; j < 4; ++j) {
      const int n = n0 + wc + j * 16 + r;
      const int m = m0 + wr + i * 16 + q * 4;
      *(floatx4*)&P[(size_t)n * DD + m] = acc[i][j];
    }
}

// ---------------------------------------------------------------------------
// K3: G_T = sum over splits of P_T. 128 blocks x 256 thr, one floatx4 each.
__global__ void reduce_g(const float* __restrict__ P_T, float* __restrict__ G_T) {
  int idx = blockIdx.x * 256 + threadIdx.x;
  int z = idx >> 14, off = idx & 16383;
  const floatx4* Pp = (const floatx4*)P_T;
  floatx4 s = (floatx4){0.f, 0.f, 0.f, 0.f};
#pragma unroll
  for (int y = 0; y < NSPLIT; ++y)
    s += Pp[(size_t)(z * NSPLIT + y) * 16384 + off];
  ((floatx4*)G_T)[idx] = s;
}

// ---------------------------------------------------------------------------
// K4: H_z = (G_z/256) @ W3seg_z via MFMA; writes Ht[m][k] bf16. 32 blocks.
// smA[k][l] <- G_T[l][k] (bf16), smB[m][l] <- W3seg[l][m] (bf16), BK=128.
__global__ __launch_bounds__(256, 1)
void h_mfma(const float* __restrict__ G_T, const float* __restrict__ W3,
            unsigned short* __restrict__ H1t, unsigned short* __restrict__ H2t)
{
  __shared__ __align__(16) unsigned short smA[64 * 136];
  __shared__ __align__(16) unsigned short smB[64 * 136];
  const int T = threadIdx.x, lane = T & 63, wv = T >> 6;
  const int q = lane >> 4, r = lane & 15;
  const int B = blockIdx.x;
  const int z = B >> 4, rr = B & 15;
  const int k0 = (rr >> 2) * 64, m0 = (rr & 3) * 64;
  const float* G = G_T + (size_t)z * 65536;
  unsigned short* Ht = z ? H2t : H1t;
  const int woff = 256 + z * 256;

  floatx4 acc[4];
#pragma unroll
  for (int j = 0; j < 4; ++j) acc[j] = (floatx4){0.f, 0.f, 0.f, 0.f};

  for (int ch = 0; ch < 2; ++ch) {
    const int lc = ch * 128;
#pragma unroll
    for (int hh = 0; hh < 2; ++hh) {
      const int l = hh * 64 + (T >> 2);
      const int sq = (T & 3) * 16;
#pragma unroll
      for (int c = 0; c < 4; ++c) {
        floatx4 g = *(const floatx4*)&G[(size_t)(lc + l) * DD + k0 + sq + c * 4];
        floatx4 w = *(const floatx4*)&W3[(size_t)(woff + lc + l) * DD + m0 + sq + c * 4];
#pragma unroll
        for (int i = 0; i < 4; ++i) {
          smA[(sq + c * 4 + i) * 136 + l] = f2bf(g[i]);
          smB[(sq + c * 4 + i) * 136 + l] = f2bf(w[i]);
        }
      }
    }
    __syncthreads();
#pragma unroll
    for (int ks = 0; ks < 4; ++ks) {
      short8 af = *(const short8*)&smA[(wv * 16 + r) * 136 + ks * 32 + q * 8];
#pragma unroll
      for (int j = 0; j < 4; ++j) {
        short8 bf = *(const short8*)&smB[(j * 16 + r) * 136 + ks * 32 + q * 8];
        acc[j] = mfma_bf16(af, bf, acc[j]);
      }
    }
    __syncthreads();
  }
#pragma unroll
  for (int j = 0; j < 4; ++j) {
    short4v v;
#pragma unroll
    for (int i = 0; i < 4; ++i) v[i] = (short)f2bf(acc[j][i] * 0.00390625f);
    *(short4v*)&Ht[(size_t)(m0 + j * 16 + r) * DD + k0 + wv * 16 + q * 4] = v;
  }
}

// ---------------------------------------------------------------------------
// K5: out = relu(x@W3a + e1@H1 + e2@H2 + b3), fp32 out. Tile 64x128, BK=64.
// seg0: A from fp32 x (cvt), B from fp32 W3 rows 0..255 (transpose-staged).
__global__ __launch_bounds__(256, 1)
void out_gemm(const float* __restrict__ x,
              const unsigned short* __restrict__ e1, const unsigned short* __restrict__ e2,
              const float* __restrict__ W3,
              const unsigned short* __restrict__ H1t, const unsigned short* __restrict__ H2t,
              const float* __restrict__ b3, float* __restrict__ out)
{
  __shared__ __align__(16) unsigned short smA[64 * 72];
  __shared__ __align__(16) unsigned short smB[128 * 72];
  const int T = threadIdx.x, lane = T & 63, wv = T >> 6;
  const int q = lane >> 4, r = lane & 15;
  const int col0 = blockIdx.x * 128, row0 = blockIdx.y * 64;

  floatx4 acc[4][2];
#pragma unroll
  for (int i = 0; i < 4; ++i)
#pragma unroll
    for (int j = 0; j < 2; ++j) acc[i][j] = (floatx4){0.f, 0.f, 0.f, 0.f};

  for (int s = 0; s < 3; ++s) {
    for (int kc = 0; kc < 256; kc += 64) {
      if (s == 0) {
#pragma unroll
        for (int p = 0; p < 4; ++p) {
          const int rr = p * 16 + (T >> 4), k4 = (T & 15) * 4;
          floatx4 v = *(const floatx4*)&x[(size_t)(row0 + rr) * DD + kc + k4];
          short4v sv;
#pragma unroll
          for (int c = 0; c < 4; ++c) sv[c] = (short)f2bf(v[c]);
          *(short4v*)&smA[rr * 72 + k4] = sv;
        }
        const int n = T & 127, khalf = T >> 7;
#pragma unroll
        for (int p = 0; p < 32; ++p) {
          const int k = p * 2 + khalf;
          smB[n * 72 + k] = f2bf(W3[(size_t)(kc + k) * DD + col0 + n]);
        }
      } else {
        const unsigned short* E = (s == 1) ? e1 : e2;
        const unsigned short* Hs = (s == 1) ? H1t : H2t;
#pragma unroll
        for (int p = 0; p < 2; ++p) {
          const int rr = p * 32 + (T >> 3), k8 = (T & 7) * 8;
          *(short8*)&smA[rr * 72 + k8] = *(const short8*)&E[(size_t)(row0 + rr) * DD + kc + k8];
        }
#pragma unroll
        for (int p = 0; p < 4; ++p) {
          const int nn = p * 32 + (T >> 3), k8 = (T & 7) * 8;
          *(short8*)&smB[nn * 72 + k8] = *(const short8*)&Hs[(size_t)(col0 + nn) * DD + kc + k8];
        }
      }
      __syncthreads();
#pragma unroll
      for (int ks = 0; ks < 2; ++ks) {
        short8 af[4], bf[2];
#pragma unroll
        for (int i = 0; i < 4; ++i)
          af[i] = *(const short8*)&smA[(i * 16 + r) * 72 + ks * 32 + q * 8];
#pragma unroll
        for (int j = 0; j < 2; ++j)
          bf[j] = *(const short8*)&smB[(wv * 32 + j * 16 + r) * 72 + ks * 32 + q * 8];
#pragma unroll
        for (int i = 0; i < 4; ++i)
#pragma unroll
          for (int j = 0; j < 2; ++j)
            acc[i][j] = mfma_bf16(af[i], bf[j], acc[i][j]);
      }
      __syncthreads();
    }
  }
#pragma unroll
  for (int j = 0; j < 2; ++j) {
    const int col = col0 + wv * 32 + j * 16 + r;
    const float bv = b3[col];
#pragma unroll
    for (int i = 0; i < 4; ++i) {
      const int rowb = row0 + i * 16 + q * 4;
#pragma unroll
      for (int t2 = 0; t2 < 4; ++t2)
        out[(size_t)(rowb + t2) * DD + col] = fmaxf(acc[i][j][t2] + bv, 0.0f);
    }
  }
}

// ---------------------------------------------------------------------------
extern "C" void kernel_launch(void* const* d_in, const int* in_sizes, int n_in,
                              void* d_out, int out_size, void* d_ws, size_t ws_size,
                              hipStream_t stream) {
  (void)in_sizes; (void)n_in; (void)out_size; (void)ws_size;
  const float* x  = (const float*)d_in[3];
  const float* W1 = (const float*)d_in[5];
  const float* b1 = (const float*)d_in[6];
  const float* W2 = (const float*)d_in[7];
  const float* b2 = (const float*)d_in[8];
  const float* W3 = (const float*)d_in[9];
  const float* b3 = (const float*)d_in[10];
  float* out = (float*)d_out;

  char* ws = (char*)d_ws;
  const size_t MB = 1u << 20;
  const size_t KB = 1u << 10;
  unsigned short* xT  = (unsigned short*)ws;                           // 4 MB
  unsigned short* e1  = (unsigned short*)(ws + 4 * MB);                // 4 MB
  unsigned short* e2  = (unsigned short*)(ws + 8 * MB);                // 4 MB
  unsigned short* e1T = (unsigned short*)(ws + 12 * MB);               // 4 MB
  unsigned short* e2T = (unsigned short*)(ws + 16 * MB);               // 4 MB
  unsigned short* H1t = (unsigned short*)(ws + 20 * MB);               // 128 KB
  unsigned short* H2t = (unsigned short*)(ws + 20 * MB + 128 * KB);    // 128 KB
  float* G_T          = (float*)(ws + 20 * MB + 256 * KB);             // 512 KB
  float* P_T          = (float*)(ws + 21 * MB);                        // 16 MB

  e_gemm<<<dim3(2, 64, 2), 256, 0, stream>>>(x, W1, b1, W2, b2, e1, e2, e1T, e2T, xT);
  atb<<<dim3(4, NSPLIT, 2), 256, 0, stream>>>(e1T, e2T, xT, P_T);
  reduce_g<<<128, 256, 0, stream>>>(P_T, G_T);
  h_mfma<<<32, 256, 0, stream>>>(G_T, W3, H1t, H2t);
  out_gemm<<<dim3(2, 128), 256, 0, stream>>>(x, e1, e2, W3, H1t, H2t, b3, out);
}